// Round 1
// baseline (814.397 us; speedup 1.0000x reference)
//
#include <hip/hip_runtime.h>

#define H 128

// C[M,H] = relu(A[M,H] @ W[H,H] + b) (+ R if non-null)
// 256 threads = 4 waves; 32 rows/block; wave handles 8 rows; lane handles cols {lane, lane+64}.
__global__ __launch_bounds__(256) void gemm_relu(
    const float* __restrict__ A, const float* __restrict__ W,
    const float* __restrict__ b, const float* __restrict__ R,
    float* __restrict__ C, int M) {
  __shared__ float lds_a[32 * H];
  const int tid = threadIdx.x;
  const int r0 = blockIdx.x * 32;
  const int rows = min(32, M - r0);

  // stage A rows (contiguous) into LDS via float4
  const float4* A4 = reinterpret_cast<const float4*>(A + (size_t)r0 * H);
  float4* L4 = reinterpret_cast<float4*>(lds_a);
  const int nf4 = rows * (H / 4);
  for (int i = tid; i < nf4; i += 256) L4[i] = A4[i];
  __syncthreads();

  const int wave = tid >> 6, lane = tid & 63;
  const int rbase = wave * 8;
  float acc0[8], acc1[8];
#pragma unroll
  for (int r = 0; r < 8; r++) { acc0[r] = 0.f; acc1[r] = 0.f; }
  const float bias0 = b[lane], bias1 = b[lane + 64];

  for (int k = 0; k < H; k++) {
    const float w0 = W[k * H + lane];
    const float w1 = W[k * H + lane + 64];
#pragma unroll
    for (int r = 0; r < 8; r++) {
      const float a = lds_a[(rbase + r) * H + k];
      acc0[r] = fmaf(a, w0, acc0[r]);
      acc1[r] = fmaf(a, w1, acc1[r]);
    }
  }

#pragma unroll
  for (int r = 0; r < 8; r++) {
    const int row = r0 + rbase + r;
    if (row < M) {
      float v0 = fmaxf(acc0[r] + bias0, 0.f);
      float v1 = fmaxf(acc1[r] + bias1, 0.f);
      if (R) {
        v0 += R[(size_t)row * H + lane];
        v1 += R[(size_t)row * H + lane + 64];
      }
      C[(size_t)row * H + lane] = v0;
      C[(size_t)row * H + lane + 64] = v1;
    }
  }
}

// one wave per edge; lane l handles float2 at column 2l of the 128-wide row
__global__ __launch_bounds__(256) void scatter_edges(
    const float* __restrict__ Y, const int* __restrict__ src,
    const int* __restrict__ tgt, const float* __restrict__ norm,
    float* __restrict__ pooled, int E) {
  const size_t t = (size_t)blockIdx.x * blockDim.x + threadIdx.x;
  const size_t e = t >> 6;
  if (e >= (size_t)E) return;
  const int lane = (int)(t & 63);
  const int s = src[e];
  const int tg = tgt[e];
  const float nm = norm[e];
  const float2 v = reinterpret_cast<const float2*>(Y + (size_t)s * H)[lane];
  float* p = pooled + (size_t)tg * H + lane * 2;
  unsafeAtomicAdd(p, nm * v.x);
  unsafeAtomicAdd(p + 1, nm * v.y);
}

extern "C" void kernel_launch(void* const* d_in, const int* in_sizes, int n_in,
                              void* d_out, int out_size, void* d_ws, size_t ws_size,
                              hipStream_t stream) {
  const float* X    = (const float*)d_in[0];
  const int*   src  = (const int*)d_in[1];
  const int*   tgt  = (const int*)d_in[2];
  const float* norm = (const float*)d_in[3];
  const float* W1   = (const float*)d_in[4];
  const float* b1   = (const float*)d_in[5];
  const float* W2   = (const float*)d_in[6];
  const float* b2   = (const float*)d_in[7];
  float* out = (float*)d_out;

  const int N = in_sizes[0] / H;   // 50000
  const int E = in_sizes[1];       // 800000

  float* Y      = (float*)d_ws;                       // N*H floats
  float* pooled = (float*)d_ws + (size_t)N * H;       // N*H floats

  hipMemsetAsync(pooled, 0, (size_t)N * H * sizeof(float), stream);

  const int gemm_blocks = (N + 31) / 32;
  gemm_relu<<<gemm_blocks, 256, 0, stream>>>(X, W1, b1, nullptr, Y, N);

  const size_t total_t = (size_t)E * 64;
  const int sc_blocks = (int)((total_t + 255) / 256);
  scatter_edges<<<sc_blocks, 256, 0, stream>>>(Y, src, tgt, norm, pooled, E);

  gemm_relu<<<gemm_blocks, 256, 0, stream>>>(pooled, W2, b2, X, out, N);
}

// Round 3
// 416.399 us; speedup vs baseline: 1.9558x; 1.9558x over previous
//
#include <hip/hip_runtime.h>

#define H 128

// C[M,H] = relu(A[M,H] @ W[H,H] + b) (+ R if non-null)
__global__ __launch_bounds__(256) void gemm_relu(
    const float* __restrict__ A, const float* __restrict__ W,
    const float* __restrict__ b, const float* __restrict__ R,
    float* __restrict__ C, int M) {
  __shared__ float lds_a[32 * H];
  const int tid = threadIdx.x;
  const int r0 = blockIdx.x * 32;
  const int rows = min(32, M - r0);

  const float4* A4 = reinterpret_cast<const float4*>(A + (size_t)r0 * H);
  float4* L4 = reinterpret_cast<float4*>(lds_a);
  const int nf4 = rows * (H / 4);
  for (int i = tid; i < nf4; i += 256) L4[i] = A4[i];
  __syncthreads();

  const int wave = tid >> 6, lane = tid & 63;
  const int rbase = wave * 8;
  float acc0[8], acc1[8];
#pragma unroll
  for (int r = 0; r < 8; r++) { acc0[r] = 0.f; acc1[r] = 0.f; }
  const float bias0 = b[lane], bias1 = b[lane + 64];

  for (int k = 0; k < H; k++) {
    const float w0 = W[k * H + lane];
    const float w1 = W[k * H + lane + 64];
#pragma unroll
    for (int r = 0; r < 8; r++) {
      const float a = lds_a[(rbase + r) * H + k];
      acc0[r] = fmaf(a, w0, acc0[r]);
      acc1[r] = fmaf(a, w1, acc1[r]);
    }
  }

#pragma unroll
  for (int r = 0; r < 8; r++) {
    const int row = r0 + rbase + r;
    if (row < M) {
      float v0 = fmaxf(acc0[r] + bias0, 0.f);
      float v1 = fmaxf(acc1[r] + bias1, 0.f);
      if (R) {
        v0 += R[(size_t)row * H + lane];
        v1 += R[(size_t)row * H + lane + 64];
      }
      C[(size_t)row * H + lane] = v0;
      C[(size_t)row * H + lane + 64] = v1;
    }
  }
}

__global__ __launch_bounds__(256) void count_tgt(
    const int* __restrict__ tgt, int* __restrict__ counts, int E) {
  int e = blockIdx.x * blockDim.x + threadIdx.x;
  if (e < E) atomicAdd(&counts[tgt[e]], 1);
}

// single-block exclusive scan: 512 threads, each owns a contiguous chunk
__global__ __launch_bounds__(512) void scan_offsets(
    const int* __restrict__ counts, int* __restrict__ offsets,
    int* __restrict__ cursor, int N, int E) {
  __shared__ int wsum[8];
  const int tid = threadIdx.x, lane = tid & 63, wv = tid >> 6;
  const int C = (N + 511) / 512;
  const int begin = tid * C;
  const int end = min(begin + C, N);

  int s = 0;
  for (int i = begin; i < end; i++) s += counts[i];

  // wave inclusive scan of per-thread sums
  int x = s;
#pragma unroll
  for (int d = 1; d < 64; d <<= 1) {
    int v = __shfl_up(x, d);
    if (lane >= d) x += v;
  }
  if (lane == 63) wsum[wv] = x;
  __syncthreads();
  if (tid == 0) {
    int a = 0;
    for (int w = 0; w < 8; w++) { int t = wsum[w]; wsum[w] = a; a += t; }
  }
  __syncthreads();

  int excl = x - s + wsum[wv];  // exclusive prefix for this thread's chunk
  for (int i = begin; i < end; i++) {
    offsets[i] = excl;
    cursor[i] = excl;
    excl += counts[i];
  }
  if (tid == 0) offsets[N] = E;
}

__global__ __launch_bounds__(256) void fill_edges(
    const int* __restrict__ src, const int* __restrict__ tgt,
    const float* __restrict__ norm, int* __restrict__ cursor,
    int2* __restrict__ pairs, int E) {
  int e = blockIdx.x * blockDim.x + threadIdx.x;
  if (e >= E) return;
  int pos = atomicAdd(&cursor[tgt[e]], 1);
  pairs[pos] = make_int2(src[e], __float_as_int(norm[e]));
}

// one wave per node: walk its edge list, gather Y rows, accumulate in regs
__global__ __launch_bounds__(256) void pull_pool(
    const float* __restrict__ Y, const int2* __restrict__ pairs,
    const int* __restrict__ offsets, float* __restrict__ pooled, int N) {
  const int node = blockIdx.x * 4 + (threadIdx.x >> 6);
  if (node >= N) return;
  const int lane = threadIdx.x & 63;
  int i = offsets[node];
  const int iend = offsets[node + 1];

  float2 acc = make_float2(0.f, 0.f);
  for (; i + 1 < iend; i += 2) {
    int2 p0 = pairs[i];
    int2 p1 = pairs[i + 1];
    float2 v0 = reinterpret_cast<const float2*>(Y + (size_t)p0.x * H)[lane];
    float2 v1 = reinterpret_cast<const float2*>(Y + (size_t)p1.x * H)[lane];
    float n0 = __int_as_float(p0.y), n1 = __int_as_float(p1.y);
    acc.x = fmaf(n0, v0.x, acc.x);
    acc.y = fmaf(n0, v0.y, acc.y);
    acc.x = fmaf(n1, v1.x, acc.x);
    acc.y = fmaf(n1, v1.y, acc.y);
  }
  if (i < iend) {
    int2 p0 = pairs[i];
    float2 v0 = reinterpret_cast<const float2*>(Y + (size_t)p0.x * H)[lane];
    float n0 = __int_as_float(p0.y);
    acc.x = fmaf(n0, v0.x, acc.x);
    acc.y = fmaf(n0, v0.y, acc.y);
  }
  reinterpret_cast<float2*>(pooled + (size_t)node * H)[lane] = acc;
}

extern "C" void kernel_launch(void* const* d_in, const int* in_sizes, int n_in,
                              void* d_out, int out_size, void* d_ws, size_t ws_size,
                              hipStream_t stream) {
  const float* X    = (const float*)d_in[0];
  const int*   src  = (const int*)d_in[1];
  const int*   tgt  = (const int*)d_in[2];
  const float* norm = (const float*)d_in[3];
  const float* W1   = (const float*)d_in[4];
  const float* b1   = (const float*)d_in[5];
  const float* W2   = (const float*)d_in[6];
  const float* b2   = (const float*)d_in[7];
  float* out = (float*)d_out;

  const int N = in_sizes[0] / H;   // 50000
  const int E = in_sizes[1];       // 800000

  // Y lives in d_out (it is dead before the final gemm overwrites d_out).
  float* Y = out;

  // workspace carve (256B-aligned) — total ~32.8 MB, must stay < ws_size
  auto align_up = [](size_t x) { return (x + 255) & ~(size_t)255; };
  char* w = (char*)d_ws;
  float* pooled  = (float*)w;  w += align_up((size_t)N * H * sizeof(float));
  int*   counts  = (int*)w;    w += align_up((size_t)N * sizeof(int));
  int*   offsets = (int*)w;    w += align_up((size_t)(N + 1) * sizeof(int));
  int*   cursor  = (int*)w;    w += align_up((size_t)N * sizeof(int));
  int2*  pairs   = (int2*)w;   w += align_up((size_t)E * sizeof(int2));

  hipMemsetAsync(counts, 0, (size_t)N * sizeof(int), stream);

  const int gemm_blocks = (N + 31) / 32;
  gemm_relu<<<gemm_blocks, 256, 0, stream>>>(X, W1, b1, nullptr, Y, N);

  const int eb = (E + 255) / 256;
  count_tgt<<<eb, 256, 0, stream>>>(tgt, counts, E);
  scan_offsets<<<1, 512, 0, stream>>>(counts, offsets, cursor, N, E);
  fill_edges<<<eb, 256, 0, stream>>>(src, tgt, norm, cursor, pairs, E);

  pull_pool<<<(N + 3) / 4, 256, 0, stream>>>(Y, pairs, offsets, pooled, N);

  gemm_relu<<<gemm_blocks, 256, 0, stream>>>(pooled, W2, b2, X, out, N);
}

// Round 4
// 306.778 us; speedup vs baseline: 2.6547x; 1.3573x over previous
//
#include <hip/hip_runtime.h>

#define H 128

// C[M,H] = relu(A[M,H] @ W[H,H] + b) (+ R if non-null)
__global__ __launch_bounds__(256) void gemm_relu(
    const float* __restrict__ A, const float* __restrict__ W,
    const float* __restrict__ b, const float* __restrict__ R,
    float* __restrict__ C, int M) {
  __shared__ float lds_a[32 * H];
  const int tid = threadIdx.x;
  const int r0 = blockIdx.x * 32;
  const int rows = min(32, M - r0);

  const float4* A4 = reinterpret_cast<const float4*>(A + (size_t)r0 * H);
  float4* L4 = reinterpret_cast<float4*>(lds_a);
  const int nf4 = rows * (H / 4);
  for (int i = tid; i < nf4; i += 256) L4[i] = A4[i];
  __syncthreads();

  const int wave = tid >> 6, lane = tid & 63;
  const int rbase = wave * 8;
  float acc0[8], acc1[8];
#pragma unroll
  for (int r = 0; r < 8; r++) { acc0[r] = 0.f; acc1[r] = 0.f; }
  const float bias0 = b[lane], bias1 = b[lane + 64];

  for (int k = 0; k < H; k++) {
    const float w0 = W[k * H + lane];
    const float w1 = W[k * H + lane + 64];
#pragma unroll
    for (int r = 0; r < 8; r++) {
      const float a = lds_a[(rbase + r) * H + k];
      acc0[r] = fmaf(a, w0, acc0[r]);
      acc1[r] = fmaf(a, w1, acc1[r]);
    }
  }

#pragma unroll
  for (int r = 0; r < 8; r++) {
    const int row = r0 + rbase + r;
    if (row < M) {
      float v0 = fmaxf(acc0[r] + bias0, 0.f);
      float v1 = fmaxf(acc1[r] + bias1, 0.f);
      if (R) {
        v0 += R[(size_t)row * H + lane];
        v1 += R[(size_t)row * H + lane + 64];
      }
      C[(size_t)row * H + lane] = v0;
      C[(size_t)row * H + lane + 64] = v1;
    }
  }
}

__global__ __launch_bounds__(256) void count_tgt(
    const int* __restrict__ tgt, int* __restrict__ counts, int E) {
  int e = blockIdx.x * blockDim.x + threadIdx.x;
  if (e < E) atomicAdd(&counts[tgt[e]], 1);
}

// --- hierarchical scan: 1024 counts per block ---

__global__ __launch_bounds__(256) void scan_partial(
    const int* __restrict__ counts, int* __restrict__ blockSums, int N) {
  const int tid = threadIdx.x;
  const int base = blockIdx.x * 1024 + tid * 4;
  int4 v = make_int4(0, 0, 0, 0);
  if (base + 3 < N) {
    v = *reinterpret_cast<const int4*>(counts + base);
  } else if (base < N) {
    const int n = N - base;
    v.x = counts[base];
    if (n > 1) v.y = counts[base + 1];
    if (n > 2) v.z = counts[base + 2];
  }
  int s = v.x + v.y + v.z + v.w;
#pragma unroll
  for (int d = 1; d < 64; d <<= 1) s += __shfl_xor(s, d);
  __shared__ int ws[4];
  if ((tid & 63) == 0) ws[tid >> 6] = s;
  __syncthreads();
  if (tid == 0) blockSums[blockIdx.x] = ws[0] + ws[1] + ws[2] + ws[3];
}

// exclusive scan of blockSums (nb entries), single wave with carry loop
__global__ __launch_bounds__(64) void scan_block_sums(
    int* __restrict__ blockSums, int nb) {
  const int lane = threadIdx.x;
  int carry = 0;
  for (int b = 0; b < nb; b += 64) {
    const int i = b + lane;
    const int v = (i < nb) ? blockSums[i] : 0;
    int x = v;
#pragma unroll
    for (int d = 1; d < 64; d <<= 1) {
      int t = __shfl_up(x, d);
      if (lane >= d) x += t;
    }
    if (i < nb) blockSums[i] = carry + x - v;  // exclusive
    carry += __shfl(x, 63);
  }
}

__global__ __launch_bounds__(256) void scan_final(
    const int* __restrict__ counts, const int* __restrict__ blockSums,
    int* __restrict__ offsets, int* __restrict__ cursor, int N, int E) {
  const int tid = threadIdx.x, lane = tid & 63, wv = tid >> 6;
  const int base = blockIdx.x * 1024 + tid * 4;
  int4 v = make_int4(0, 0, 0, 0);
  if (base + 3 < N) {
    v = *reinterpret_cast<const int4*>(counts + base);
  } else if (base < N) {
    const int n = N - base;
    v.x = counts[base];
    if (n > 1) v.y = counts[base + 1];
    if (n > 2) v.z = counts[base + 2];
  }
  const int s = v.x + v.y + v.z + v.w;
  int x = s;
#pragma unroll
  for (int d = 1; d < 64; d <<= 1) {
    int t = __shfl_up(x, d);
    if (lane >= d) x += t;
  }
  __shared__ int ws[4];
  if (lane == 63) ws[wv] = x;
  __syncthreads();
  int wbase = 0;
  for (int i = 0; i < wv; i++) wbase += ws[i];

  const int excl = blockSums[blockIdx.x] + wbase + (x - s);
  const int o0 = excl, o1 = o0 + v.x, o2 = o1 + v.y, o3 = o2 + v.z;
  if (base + 3 < N) {
    *reinterpret_cast<int4*>(offsets + base) = make_int4(o0, o1, o2, o3);
    *reinterpret_cast<int4*>(cursor + base) = make_int4(o0, o1, o2, o3);
  } else if (base < N) {
    const int n = N - base;
    offsets[base] = o0; cursor[base] = o0;
    if (n > 1) { offsets[base + 1] = o1; cursor[base + 1] = o1; }
    if (n > 2) { offsets[base + 2] = o2; cursor[base + 2] = o2; }
  }
  if (blockIdx.x == 0 && tid == 0) offsets[N] = E;
}

__global__ __launch_bounds__(256) void fill_edges(
    const int* __restrict__ src, const int* __restrict__ tgt,
    const float* __restrict__ norm, int* __restrict__ cursor,
    int2* __restrict__ pairs, int E) {
  int e = blockIdx.x * blockDim.x + threadIdx.x;
  if (e >= E) return;
  int pos = atomicAdd(&cursor[tgt[e]], 1);
  pairs[pos] = make_int2(src[e], __float_as_int(norm[e]));
}

// one wave per node: walk its edge list, gather Y rows, accumulate in regs
__global__ __launch_bounds__(256) void pull_pool(
    const float* __restrict__ Y, const int2* __restrict__ pairs,
    const int* __restrict__ offsets, float* __restrict__ pooled, int N) {
  const int node = blockIdx.x * 4 + (threadIdx.x >> 6);
  if (node >= N) return;
  const int lane = threadIdx.x & 63;
  int i = offsets[node];
  const int iend = offsets[node + 1];

  float2 acc = make_float2(0.f, 0.f);
  for (; i + 1 < iend; i += 2) {
    int2 p0 = pairs[i];
    int2 p1 = pairs[i + 1];
    float2 v0 = reinterpret_cast<const float2*>(Y + (size_t)p0.x * H)[lane];
    float2 v1 = reinterpret_cast<const float2*>(Y + (size_t)p1.x * H)[lane];
    float n0 = __int_as_float(p0.y), n1 = __int_as_float(p1.y);
    acc.x = fmaf(n0, v0.x, acc.x);
    acc.y = fmaf(n0, v0.y, acc.y);
    acc.x = fmaf(n1, v1.x, acc.x);
    acc.y = fmaf(n1, v1.y, acc.y);
  }
  if (i < iend) {
    int2 p0 = pairs[i];
    float2 v0 = reinterpret_cast<const float2*>(Y + (size_t)p0.x * H)[lane];
    float n0 = __int_as_float(p0.y);
    acc.x = fmaf(n0, v0.x, acc.x);
    acc.y = fmaf(n0, v0.y, acc.y);
  }
  reinterpret_cast<float2*>(pooled + (size_t)node * H)[lane] = acc;
}

extern "C" void kernel_launch(void* const* d_in, const int* in_sizes, int n_in,
                              void* d_out, int out_size, void* d_ws, size_t ws_size,
                              hipStream_t stream) {
  const float* X    = (const float*)d_in[0];
  const int*   src  = (const int*)d_in[1];
  const int*   tgt  = (const int*)d_in[2];
  const float* norm = (const float*)d_in[3];
  const float* W1   = (const float*)d_in[4];
  const float* b1   = (const float*)d_in[5];
  const float* W2   = (const float*)d_in[6];
  const float* b2   = (const float*)d_in[7];
  float* out = (float*)d_out;

  const int N = in_sizes[0] / H;   // 50000
  const int E = in_sizes[1];       // 800000

  // Y lives in d_out (dead before the final gemm overwrites d_out).
  float* Y = out;

  // workspace carve (256B-aligned) — total ~32.8 MB
  auto align_up = [](size_t x) { return (x + 255) & ~(size_t)255; };
  char* w = (char*)d_ws;
  float* pooled   = (float*)w;  w += align_up((size_t)N * H * sizeof(float));
  int*   counts   = (int*)w;    w += align_up((size_t)N * sizeof(int));
  int*   offsets  = (int*)w;    w += align_up((size_t)(N + 1) * sizeof(int));
  int*   cursor   = (int*)w;    w += align_up((size_t)N * sizeof(int));
  int*   blockSums= (int*)w;    w += align_up((size_t)1024 * sizeof(int));
  int2*  pairs    = (int2*)w;   w += align_up((size_t)E * sizeof(int2));

  hipMemsetAsync(counts, 0, (size_t)N * sizeof(int), stream);

  const int gemm_blocks = (N + 31) / 32;
  gemm_relu<<<gemm_blocks, 256, 0, stream>>>(X, W1, b1, nullptr, Y, N);

  const int eb = (E + 255) / 256;
  count_tgt<<<eb, 256, 0, stream>>>(tgt, counts, E);

  const int nb = (N + 1023) / 1024;  // 49
  scan_partial<<<nb, 256, 0, stream>>>(counts, blockSums, N);
  scan_block_sums<<<1, 64, 0, stream>>>(blockSums, nb);
  scan_final<<<nb, 256, 0, stream>>>(counts, blockSums, offsets, cursor, N, E);

  fill_edges<<<eb, 256, 0, stream>>>(src, tgt, norm, cursor, pairs, E);

  pull_pool<<<(N + 3) / 4, 256, 0, stream>>>(Y, pairs, offsets, pooled, N);

  gemm_relu<<<gemm_blocks, 256, 0, stream>>>(pooled, W2, b2, X, out, N);
}

// Round 5
// 274.208 us; speedup vs baseline: 2.9700x; 1.1188x over previous
//
#include <hip/hip_runtime.h>

#define H 128

typedef short short8 __attribute__((ext_vector_type(8)));
typedef float floatx4 __attribute__((ext_vector_type(4)));

__device__ __forceinline__ short f2bf(float f) {
  union { float f; unsigned u; } v; v.f = f;
  unsigned r = v.u + 0x7fffu + ((v.u >> 16) & 1u);  // RNE
  return (short)(r >> 16);
}
__device__ __forceinline__ float bf2f(unsigned u16) {
  union { unsigned u; float f; } v; v.u = u16 << 16;
  return v.f;
}

// Pack W (fp32 [K=128][N=128]) into MFMA B-fragment order:
// Bp[((nt*4+ks)*64+lane)*8 + j] = bf16(W[ks*32+(lane>>4)*8+j][nt*16+(lane&15)])
__global__ __launch_bounds__(256) void pack_W(
    const float* __restrict__ W1, const float* __restrict__ W2,
    short* __restrict__ Bp1, short* __restrict__ Bp2) {
  const int t = blockIdx.x * 256 + threadIdx.x;  // 0..4095
  const float* W = (t >> 11) ? W2 : W1;
  short* Bp = (t >> 11) ? Bp2 : Bp1;
  const int i = t & 2047;  // [nt(8)][ks(4)][lane(64)]
  const int lane = i & 63, ks = (i >> 6) & 3, nt = i >> 8;
  const int n = nt * 16 + (lane & 15);
  const int k0 = ks * 32 + ((lane >> 4) << 3);
  short8 v;
#pragma unroll
  for (int j = 0; j < 8; j++) v[j] = f2bf(W[(k0 + j) * H + n]);
  *reinterpret_cast<short8*>(Bp + (size_t)i * 8) = v;
}

// C[M,128] = relu(A[M,128] @ W + bias) (+R), A fp32 or bf16, C fp32 or bf16.
// 128 threads = 2 waves; wave handles 32 rows x 128 cols; B held in VGPRs.
template <bool A_BF16, bool C_BF16, bool RESID>
__global__ __launch_bounds__(128) void gemm_mfma(
    const void* __restrict__ Av, const short* __restrict__ Bp,
    const float* __restrict__ bias, const float* __restrict__ R,
    void* __restrict__ Cv, int M) {
  const int wv = threadIdx.x >> 6;
  const int lane = threadIdx.x & 63;
  const int m0 = blockIdx.x * 64 + wv * 32;

  short8 bf[8][4];
#pragma unroll
  for (int nt = 0; nt < 8; nt++)
#pragma unroll
    for (int ks = 0; ks < 4; ks++)
      bf[nt][ks] = *reinterpret_cast<const short8*>(
          Bp + (size_t)(((nt << 2) | ks) * 64 + lane) * 8);

  floatx4 acc[2][8];
#pragma unroll
  for (int f = 0; f < 2; f++)
#pragma unroll
    for (int nt = 0; nt < 8; nt++) acc[f][nt] = (floatx4)0.f;

  const int arow = lane & 15;
  const int kb = (lane >> 4) << 3;

#pragma unroll
  for (int ks = 0; ks < 4; ks++) {
    short8 af[2];
#pragma unroll
    for (int f = 0; f < 2; f++) {
      int row = m0 + f * 16 + arow;
      row = min(row, M - 1);  // clamp; garbage rows are never stored
      const size_t off = (size_t)row * H + (ks << 5) + kb;
      if (A_BF16) {
        af[f] = *reinterpret_cast<const short8*>((const short*)Av + off);
      } else {
        const float* ap = (const float*)Av + off;
        floatx4 x0 = *reinterpret_cast<const floatx4*>(ap);
        floatx4 x1 = *reinterpret_cast<const floatx4*>(ap + 4);
        short8 t;
        t[0] = f2bf(x0[0]); t[1] = f2bf(x0[1]);
        t[2] = f2bf(x0[2]); t[3] = f2bf(x0[3]);
        t[4] = f2bf(x1[0]); t[5] = f2bf(x1[1]);
        t[6] = f2bf(x1[2]); t[7] = f2bf(x1[3]);
        af[f] = t;
      }
    }
#pragma unroll
    for (int nt = 0; nt < 8; nt++) {
      acc[0][nt] = __builtin_amdgcn_mfma_f32_16x16x32_bf16(af[0], bf[nt][ks], acc[0][nt], 0, 0, 0);
      acc[1][nt] = __builtin_amdgcn_mfma_f32_16x16x32_bf16(af[1], bf[nt][ks], acc[1][nt], 0, 0, 0);
    }
  }

  // epilogue: C row = (lane>>4)*4 + reg, col = nt*16 + (lane&15)
  const int crow = (lane >> 4) << 2;
  const int ccol = lane & 15;
#pragma unroll
  for (int f = 0; f < 2; f++) {
#pragma unroll
    for (int nt = 0; nt < 8; nt++) {
      const int col = (nt << 4) + ccol;
      const float bv = bias[col];
#pragma unroll
      for (int r = 0; r < 4; r++) {
        const int row = m0 + f * 16 + crow + r;
        if (row < M) {
          float v = fmaxf(acc[f][nt][r] + bv, 0.f);
          if (RESID) v += R[(size_t)row * H + col];
          if (C_BF16)
            ((short*)Cv)[(size_t)row * H + col] = f2bf(v);
          else
            ((float*)Cv)[(size_t)row * H + col] = v;
        }
      }
    }
  }
}

__global__ __launch_bounds__(256) void count_tgt(
    const int* __restrict__ tgt, int* __restrict__ counts, int E) {
  int e = blockIdx.x * blockDim.x + threadIdx.x;
  if (e < E) atomicAdd(&counts[tgt[e]], 1);
}

// --- hierarchical scan: 1024 counts per block ---

__global__ __launch_bounds__(256) void scan_partial(
    const int* __restrict__ counts, int* __restrict__ blockSums, int N) {
  const int tid = threadIdx.x;
  const int base = blockIdx.x * 1024 + tid * 4;
  int4 v = make_int4(0, 0, 0, 0);
  if (base + 3 < N) {
    v = *reinterpret_cast<const int4*>(counts + base);
  } else if (base < N) {
    const int n = N - base;
    v.x = counts[base];
    if (n > 1) v.y = counts[base + 1];
    if (n > 2) v.z = counts[base + 2];
  }
  int s = v.x + v.y + v.z + v.w;
#pragma unroll
  for (int d = 1; d < 64; d <<= 1) s += __shfl_xor(s, d);
  __shared__ int ws[4];
  if ((tid & 63) == 0) ws[tid >> 6] = s;
  __syncthreads();
  if (tid == 0) blockSums[blockIdx.x] = ws[0] + ws[1] + ws[2] + ws[3];
}

__global__ __launch_bounds__(64) void scan_block_sums(
    int* __restrict__ blockSums, int nb) {
  const int lane = threadIdx.x;
  int carry = 0;
  for (int b = 0; b < nb; b += 64) {
    const int i = b + lane;
    const int v = (i < nb) ? blockSums[i] : 0;
    int x = v;
#pragma unroll
    for (int d = 1; d < 64; d <<= 1) {
      int t = __shfl_up(x, d);
      if (lane >= d) x += t;
    }
    if (i < nb) blockSums[i] = carry + x - v;  // exclusive
    carry += __shfl(x, 63);
  }
}

__global__ __launch_bounds__(256) void scan_final(
    const int* __restrict__ counts, const int* __restrict__ blockSums,
    int* __restrict__ offsets, int* __restrict__ cursor, int N, int E) {
  const int tid = threadIdx.x, lane = tid & 63, wv = tid >> 6;
  const int base = blockIdx.x * 1024 + tid * 4;
  int4 v = make_int4(0, 0, 0, 0);
  if (base + 3 < N) {
    v = *reinterpret_cast<const int4*>(counts + base);
  } else if (base < N) {
    const int n = N - base;
    v.x = counts[base];
    if (n > 1) v.y = counts[base + 1];
    if (n > 2) v.z = counts[base + 2];
  }
  const int s = v.x + v.y + v.z + v.w;
  int x = s;
#pragma unroll
  for (int d = 1; d < 64; d <<= 1) {
    int t = __shfl_up(x, d);
    if (lane >= d) x += t;
  }
  __shared__ int ws[4];
  if (lane == 63) ws[wv] = x;
  __syncthreads();
  int wbase = 0;
  for (int i = 0; i < wv; i++) wbase += ws[i];

  const int excl = blockSums[blockIdx.x] + wbase + (x - s);
  const int o0 = excl, o1 = o0 + v.x, o2 = o1 + v.y, o3 = o2 + v.z;
  if (base + 3 < N) {
    *reinterpret_cast<int4*>(offsets + base) = make_int4(o0, o1, o2, o3);
    *reinterpret_cast<int4*>(cursor + base) = make_int4(o0, o1, o2, o3);
  } else if (base < N) {
    const int n = N - base;
    offsets[base] = o0; cursor[base] = o0;
    if (n > 1) { offsets[base + 1] = o1; cursor[base + 1] = o1; }
    if (n > 2) { offsets[base + 2] = o2; cursor[base + 2] = o2; }
  }
  if (blockIdx.x == 0 && tid == 0) offsets[N] = E;
}

__global__ __launch_bounds__(256) void fill_edges(
    const int* __restrict__ src, const int* __restrict__ tgt,
    const float* __restrict__ norm, int* __restrict__ cursor,
    int2* __restrict__ pairs, int E) {
  int e = blockIdx.x * blockDim.x + threadIdx.x;
  if (e >= E) return;
  int pos = atomicAdd(&cursor[tgt[e]], 1);
  pairs[pos] = make_int2(src[e], __float_as_int(norm[e]));
}

// one wave per node: gather bf16 Y rows, accumulate fp32, store bf16 pooled
__global__ __launch_bounds__(256) void pull_pool(
    const unsigned short* __restrict__ Y, const int2* __restrict__ pairs,
    const int* __restrict__ offsets, unsigned* __restrict__ pooled, int N) {
  const int node = blockIdx.x * 4 + (threadIdx.x >> 6);
  if (node >= N) return;
  const int lane = threadIdx.x & 63;
  int i = offsets[node];
  const int iend = offsets[node + 1];

  float ax = 0.f, ay = 0.f;
  for (; i + 1 < iend; i += 2) {
    int2 p0 = pairs[i], p1 = pairs[i + 1];
    unsigned v0 = *reinterpret_cast<const unsigned*>(Y + (size_t)p0.x * H + lane * 2);
    unsigned v1 = *reinterpret_cast<const unsigned*>(Y + (size_t)p1.x * H + lane * 2);
    float n0 = __int_as_float(p0.y), n1 = __int_as_float(p1.y);
    ax = fmaf(n0, bf2f(v0 & 0xffffu), ax);
    ay = fmaf(n0, bf2f(v0 >> 16), ay);
    ax = fmaf(n1, bf2f(v1 & 0xffffu), ax);
    ay = fmaf(n1, bf2f(v1 >> 16), ay);
  }
  if (i < iend) {
    int2 p0 = pairs[i];
    unsigned v0 = *reinterpret_cast<const unsigned*>(Y + (size_t)p0.x * H + lane * 2);
    float n0 = __int_as_float(p0.y);
    ax = fmaf(n0, bf2f(v0 & 0xffffu), ax);
    ay = fmaf(n0, bf2f(v0 >> 16), ay);
  }
  pooled[(size_t)node * 64 + lane] =
      ((unsigned)(unsigned short)f2bf(ay) << 16) | (unsigned short)f2bf(ax);
}

extern "C" void kernel_launch(void* const* d_in, const int* in_sizes, int n_in,
                              void* d_out, int out_size, void* d_ws, size_t ws_size,
                              hipStream_t stream) {
  const float* X    = (const float*)d_in[0];
  const int*   src  = (const int*)d_in[1];
  const int*   tgt  = (const int*)d_in[2];
  const float* norm = (const float*)d_in[3];
  const float* W1   = (const float*)d_in[4];
  const float* b1   = (const float*)d_in[5];
  const float* W2   = (const float*)d_in[6];
  const float* b2   = (const float*)d_in[7];
  float* out = (float*)d_out;

  const int N = in_sizes[0] / H;   // 50000
  const int E = in_sizes[1];       // 800000

  // workspace carve (256B-aligned) — ~33 MB
  auto align_up = [](size_t x) { return (x + 255) & ~(size_t)255; };
  char* w = (char*)d_ws;
  unsigned short* Ybf   = (unsigned short*)w; w += align_up((size_t)N * H * 2);
  unsigned short* pool  = (unsigned short*)w; w += align_up((size_t)N * H * 2);
  int*   counts   = (int*)w;   w += align_up((size_t)N * sizeof(int));
  int*   offsets  = (int*)w;   w += align_up((size_t)(N + 1) * sizeof(int));
  int*   cursor   = (int*)w;   w += align_up((size_t)N * sizeof(int));
  int*   blockSums= (int*)w;   w += align_up((size_t)1024 * sizeof(int));
  short* Bp1      = (short*)w; w += align_up((size_t)16384 * sizeof(short));
  short* Bp2      = (short*)w; w += align_up((size_t)16384 * sizeof(short));
  int2*  pairs    = (int2*)w;  w += align_up((size_t)E * sizeof(int2));

  hipMemsetAsync(counts, 0, (size_t)N * sizeof(int), stream);

  pack_W<<<16, 256, 0, stream>>>(W1, W2, Bp1, Bp2);

  const int gemm_blocks = (N + 63) / 64;  // 782
  gemm_mfma<false, true, false><<<gemm_blocks, 128, 0, stream>>>(
      X, Bp1, b1, nullptr, Ybf, N);

  const int eb = (E + 255) / 256;
  count_tgt<<<eb, 256, 0, stream>>>(tgt, counts, E);

  const int nb = (N + 1023) / 1024;  // 49
  scan_partial<<<nb, 256, 0, stream>>>(counts, blockSums, N);
  scan_block_sums<<<1, 64, 0, stream>>>(blockSums, nb);
  scan_final<<<nb, 256, 0, stream>>>(counts, blockSums, offsets, cursor, N, E);

  fill_edges<<<eb, 256, 0, stream>>>(src, tgt, norm, cursor, pairs, E);

  pull_pool<<<(N + 3) / 4, 256, 0, stream>>>(
      Ybf, pairs, offsets, (unsigned*)pool, N);

  gemm_mfma<true, false, true><<<gemm_blocks, 128, 0, stream>>>(
      pool, Bp2, b2, X, out, N);
}

// Round 6
// 233.217 us; speedup vs baseline: 3.4920x; 1.1758x over previous
//
#include <hip/hip_runtime.h>

#define H 128

typedef short short8 __attribute__((ext_vector_type(8)));
typedef float floatx4 __attribute__((ext_vector_type(4)));

__device__ __forceinline__ short f2bf(float f) {
  union { float f; unsigned u; } v; v.f = f;
  unsigned r = v.u + 0x7fffu + ((v.u >> 16) & 1u);  // RNE
  return (short)(r >> 16);
}
__device__ __forceinline__ float bf2f(unsigned u16) {
  union { unsigned u; float f; } v; v.u = u16 << 16;
  return v.f;
}

// first 16 blocks: pack W1/W2 into MFMA B-fragment order; rest: count + rank
// Bp[((nt*4+ks)*64+lane)*8 + j] = bf16(W[ks*32+(lane>>4)*8+j][nt*16+(lane&15)])
__global__ __launch_bounds__(256) void pack_count(
    const float* __restrict__ W1, const float* __restrict__ W2,
    short* __restrict__ Bp1, short* __restrict__ Bp2,
    const int* __restrict__ tgt, int* __restrict__ counts,
    int* __restrict__ rank, int E) {
  if (blockIdx.x < 16) {
    const int t = blockIdx.x * 256 + threadIdx.x;  // 0..4095
    const float* W = (t >> 11) ? W2 : W1;
    short* Bp = (t >> 11) ? Bp2 : Bp1;
    const int i = t & 2047;  // [nt(8)][ks(4)][lane(64)]
    const int lane = i & 63, ks = (i >> 6) & 3, nt = i >> 8;
    const int n = nt * 16 + (lane & 15);
    const int k0 = ks * 32 + ((lane >> 4) << 3);
    short8 v;
#pragma unroll
    for (int j = 0; j < 8; j++) v[j] = f2bf(W[(k0 + j) * H + n]);
    *reinterpret_cast<short8*>(Bp + (size_t)i * 8) = v;
  } else {
    const int e = (blockIdx.x - 16) * 256 + threadIdx.x;
    if (e < E) rank[e] = atomicAdd(&counts[tgt[e]], 1);
  }
}

// C[M,128] = relu(A[M,128] @ W + bias) (+R), A fp32 or bf16, C fp32 or bf16.
// 128 threads = 2 waves; wave handles 32 rows x 128 cols; B held in VGPRs.
template <bool A_BF16, bool C_BF16, bool RESID>
__global__ __launch_bounds__(128) void gemm_mfma(
    const void* __restrict__ Av, const short* __restrict__ Bp,
    const float* __restrict__ bias, const float* __restrict__ R,
    void* __restrict__ Cv, int M) {
  const int wv = threadIdx.x >> 6;
  const int lane = threadIdx.x & 63;
  const int m0 = blockIdx.x * 64 + wv * 32;

  short8 bf[8][4];
#pragma unroll
  for (int nt = 0; nt < 8; nt++)
#pragma unroll
    for (int ks = 0; ks < 4; ks++)
      bf[nt][ks] = *reinterpret_cast<const short8*>(
          Bp + (size_t)(((nt << 2) | ks) * 64 + lane) * 8);

  floatx4 acc[2][8];
#pragma unroll
  for (int f = 0; f < 2; f++)
#pragma unroll
    for (int nt = 0; nt < 8; nt++) acc[f][nt] = (floatx4)0.f;

  const int arow = lane & 15;
  const int kb = (lane >> 4) << 3;

#pragma unroll
  for (int ks = 0; ks < 4; ks++) {
    short8 af[2];
#pragma unroll
    for (int f = 0; f < 2; f++) {
      int row = m0 + f * 16 + arow;
      row = min(row, M - 1);  // clamp; garbage rows are never stored
      const size_t off = (size_t)row * H + (ks << 5) + kb;
      if (A_BF16) {
        af[f] = *reinterpret_cast<const short8*>((const short*)Av + off);
      } else {
        const float* ap = (const float*)Av + off;
        floatx4 x0 = *reinterpret_cast<const floatx4*>(ap);
        floatx4 x1 = *reinterpret_cast<const floatx4*>(ap + 4);
        short8 t;
        t[0] = f2bf(x0[0]); t[1] = f2bf(x0[1]);
        t[2] = f2bf(x0[2]); t[3] = f2bf(x0[3]);
        t[4] = f2bf(x1[0]); t[5] = f2bf(x1[1]);
        t[6] = f2bf(x1[2]); t[7] = f2bf(x1[3]);
        af[f] = t;
      }
    }
#pragma unroll
    for (int nt = 0; nt < 8; nt++) {
      acc[0][nt] = __builtin_amdgcn_mfma_f32_16x16x32_bf16(af[0], bf[nt][ks], acc[0][nt], 0, 0, 0);
      acc[1][nt] = __builtin_amdgcn_mfma_f32_16x16x32_bf16(af[1], bf[nt][ks], acc[1][nt], 0, 0, 0);
    }
  }

  // epilogue: C row = (lane>>4)*4 + reg, col = nt*16 + (lane&15)
  const int crow = (lane >> 4) << 2;
  const int ccol = lane & 15;
#pragma unroll
  for (int f = 0; f < 2; f++) {
#pragma unroll
    for (int nt = 0; nt < 8; nt++) {
      const int col = (nt << 4) + ccol;
      const float bv = bias[col];
#pragma unroll
      for (int r = 0; r < 4; r++) {
        const int row = m0 + f * 16 + crow + r;
        if (row < M) {
          float v = fmaxf(acc[f][nt][r] + bv, 0.f);
          if (RESID) v += R[(size_t)row * H + col];
          if (C_BF16)
            ((short*)Cv)[(size_t)row * H + col] = f2bf(v);
          else
            ((float*)Cv)[(size_t)row * H + col] = v;
        }
      }
    }
  }
}

// --- hierarchical scan: 1024 counts per block ---

__global__ __launch_bounds__(256) void scan_partial(
    const int* __restrict__ counts, int* __restrict__ blockSums, int N) {
  const int tid = threadIdx.x;
  const int base = blockIdx.x * 1024 + tid * 4;
  int4 v = make_int4(0, 0, 0, 0);
  if (base + 3 < N) {
    v = *reinterpret_cast<const int4*>(counts + base);
  } else if (base < N) {
    const int n = N - base;
    v.x = counts[base];
    if (n > 1) v.y = counts[base + 1];
    if (n > 2) v.z = counts[base + 2];
  }
  int s = v.x + v.y + v.z + v.w;
#pragma unroll
  for (int d = 1; d < 64; d <<= 1) s += __shfl_xor(s, d);
  __shared__ int ws[4];
  if ((tid & 63) == 0) ws[tid >> 6] = s;
  __syncthreads();
  if (tid == 0) blockSums[blockIdx.x] = ws[0] + ws[1] + ws[2] + ws[3];
}

__global__ __launch_bounds__(64) void scan_block_sums(
    int* __restrict__ blockSums, int nb) {
  const int lane = threadIdx.x;
  int carry = 0;
  for (int b = 0; b < nb; b += 64) {
    const int i = b + lane;
    const int v = (i < nb) ? blockSums[i] : 0;
    int x = v;
#pragma unroll
    for (int d = 1; d < 64; d <<= 1) {
      int t = __shfl_up(x, d);
      if (lane >= d) x += t;
    }
    if (i < nb) blockSums[i] = carry + x - v;  // exclusive
    carry += __shfl(x, 63);
  }
}

__global__ __launch_bounds__(256) void scan_final(
    const int* __restrict__ counts, const int* __restrict__ blockSums,
    int* __restrict__ offsets, int N, int E) {
  const int tid = threadIdx.x, lane = tid & 63, wv = tid >> 6;
  const int base = blockIdx.x * 1024 + tid * 4;
  int4 v = make_int4(0, 0, 0, 0);
  if (base + 3 < N) {
    v = *reinterpret_cast<const int4*>(counts + base);
  } else if (base < N) {
    const int n = N - base;
    v.x = counts[base];
    if (n > 1) v.y = counts[base + 1];
    if (n > 2) v.z = counts[base + 2];
  }
  const int s = v.x + v.y + v.z + v.w;
  int x = s;
#pragma unroll
  for (int d = 1; d < 64; d <<= 1) {
    int t = __shfl_up(x, d);
    if (lane >= d) x += t;
  }
  __shared__ int ws[4];
  if (lane == 63) ws[wv] = x;
  __syncthreads();
  int wbase = 0;
  for (int i = 0; i < wv; i++) wbase += ws[i];

  const int excl = blockSums[blockIdx.x] + wbase + (x - s);
  const int o0 = excl, o1 = o0 + v.x, o2 = o1 + v.y, o3 = o2 + v.z;
  if (base + 3 < N) {
    *reinterpret_cast<int4*>(offsets + base) = make_int4(o0, o1, o2, o3);
  } else if (base < N) {
    const int n = N - base;
    offsets[base] = o0;
    if (n > 1) offsets[base + 1] = o1;
    if (n > 2) offsets[base + 2] = o2;
  }
  if (blockIdx.x == 0 && tid == 0) offsets[N] = E;
}

// atomic-free scatter using precomputed rank
__global__ __launch_bounds__(256) void fill_edges(
    const int* __restrict__ src, const int* __restrict__ tgt,
    const float* __restrict__ norm, const int* __restrict__ offsets,
    const int* __restrict__ rank, int2* __restrict__ pairs, int E) {
  int e = blockIdx.x * blockDim.x + threadIdx.x;
  if (e >= E) return;
  const int pos = offsets[tgt[e]] + rank[e];
  pairs[pos] = make_int2(src[e], __float_as_int(norm[e]));
}

// one wave per node: gather bf16 Y rows, fp32 accumulate, bf16 store; ILP x4
__global__ __launch_bounds__(256) void pull_pool(
    const unsigned short* __restrict__ Y, const int2* __restrict__ pairs,
    const int* __restrict__ offsets, unsigned* __restrict__ pooled, int N) {
  const int node = blockIdx.x * 4 + (threadIdx.x >> 6);
  if (node >= N) return;
  const int lane = threadIdx.x & 63;
  int i = offsets[node];
  const int iend = offsets[node + 1];

  float ax = 0.f, ay = 0.f;
  for (; i + 3 < iend; i += 4) {
    const int4 q0 = *reinterpret_cast<const int4*>(pairs + i);
    const int4 q1 = *reinterpret_cast<const int4*>(pairs + i + 2);
    const unsigned v0 = *reinterpret_cast<const unsigned*>(Y + (size_t)q0.x * H + lane * 2);
    const unsigned v1 = *reinterpret_cast<const unsigned*>(Y + (size_t)q0.z * H + lane * 2);
    const unsigned v2 = *reinterpret_cast<const unsigned*>(Y + (size_t)q1.x * H + lane * 2);
    const unsigned v3 = *reinterpret_cast<const unsigned*>(Y + (size_t)q1.z * H + lane * 2);
    const float n0 = __int_as_float(q0.y), n1 = __int_as_float(q0.w);
    const float n2 = __int_as_float(q1.y), n3 = __int_as_float(q1.w);
    ax = fmaf(n0, bf2f(v0 & 0xffffu), ax);
    ay = fmaf(n0, bf2f(v0 >> 16), ay);
    ax = fmaf(n1, bf2f(v1 & 0xffffu), ax);
    ay = fmaf(n1, bf2f(v1 >> 16), ay);
    ax = fmaf(n2, bf2f(v2 & 0xffffu), ax);
    ay = fmaf(n2, bf2f(v2 >> 16), ay);
    ax = fmaf(n3, bf2f(v3 & 0xffffu), ax);
    ay = fmaf(n3, bf2f(v3 >> 16), ay);
  }
  for (; i < iend; i++) {
    const int2 p0 = pairs[i];
    const unsigned v0 = *reinterpret_cast<const unsigned*>(Y + (size_t)p0.x * H + lane * 2);
    const float n0 = __int_as_float(p0.y);
    ax = fmaf(n0, bf2f(v0 & 0xffffu), ax);
    ay = fmaf(n0, bf2f(v0 >> 16), ay);
  }
  pooled[(size_t)node * 64 + lane] =
      ((unsigned)(unsigned short)f2bf(ay) << 16) | (unsigned short)f2bf(ax);
}

extern "C" void kernel_launch(void* const* d_in, const int* in_sizes, int n_in,
                              void* d_out, int out_size, void* d_ws, size_t ws_size,
                              hipStream_t stream) {
  const float* X    = (const float*)d_in[0];
  const int*   src  = (const int*)d_in[1];
  const int*   tgt  = (const int*)d_in[2];
  const float* norm = (const float*)d_in[3];
  const float* W1   = (const float*)d_in[4];
  const float* b1   = (const float*)d_in[5];
  const float* W2   = (const float*)d_in[6];
  const float* b2   = (const float*)d_in[7];
  float* out = (float*)d_out;

  const int N = in_sizes[0] / H;   // 50000
  const int E = in_sizes[1];       // 800000

  // workspace carve (256B-aligned) — ~36 MB
  auto align_up = [](size_t x) { return (x + 255) & ~(size_t)255; };
  char* w = (char*)d_ws;
  unsigned short* Ybf   = (unsigned short*)w; w += align_up((size_t)N * H * 2);
  unsigned short* pool  = (unsigned short*)w; w += align_up((size_t)N * H * 2);
  int*   counts   = (int*)w;   w += align_up((size_t)N * sizeof(int));
  int*   offsets  = (int*)w;   w += align_up((size_t)(N + 1) * sizeof(int));
  int*   rank     = (int*)w;   w += align_up((size_t)E * sizeof(int));
  int*   blockSums= (int*)w;   w += align_up((size_t)1024 * sizeof(int));
  short* Bp1      = (short*)w; w += align_up((size_t)16384 * sizeof(short));
  short* Bp2      = (short*)w; w += align_up((size_t)16384 * sizeof(short));
  int2*  pairs    = (int2*)w;  w += align_up((size_t)E * sizeof(int2));

  hipMemsetAsync(counts, 0, (size_t)N * sizeof(int), stream);

  const int eb = (E + 255) / 256;  // 3125
  pack_count<<<eb + 16, 256, 0, stream>>>(W1, W2, Bp1, Bp2, tgt, counts, rank, E);

  const int gemm_blocks = (N + 63) / 64;  // 782
  gemm_mfma<false, true, false><<<gemm_blocks, 128, 0, stream>>>(
      X, Bp1, b1, nullptr, Ybf, N);

  const int nb = (N + 1023) / 1024;  // 49
  scan_partial<<<nb, 256, 0, stream>>>(counts, blockSums, N);
  scan_block_sums<<<1, 64, 0, stream>>>(blockSums, nb);
  scan_final<<<nb, 256, 0, stream>>>(counts, blockSums, offsets, N, E);

  fill_edges<<<eb, 256, 0, stream>>>(src, tgt, norm, offsets, rank, pairs, E);

  pull_pool<<<(N + 3) / 4, 256, 0, stream>>>(
      Ybf, pairs, offsets, (unsigned*)pool, N);

  gemm_mfma<true, false, true><<<gemm_blocks, 128, 0, stream>>>(
      pool, Bp2, b2, X, out, N);
}

// Round 7
// 220.743 us; speedup vs baseline: 3.6893x; 1.0565x over previous
//
#include <hip/hip_runtime.h>

#define H 128

typedef short short8 __attribute__((ext_vector_type(8)));
typedef float floatx4 __attribute__((ext_vector_type(4)));

__device__ __forceinline__ short f2bf(float f) {
  union { float f; unsigned u; } v; v.f = f;
  unsigned r = v.u + 0x7fffu + ((v.u >> 16) & 1u);  // RNE
  return (short)(r >> 16);
}
__device__ __forceinline__ float bf2f(unsigned u16) {
  union { unsigned u; float f; } v; v.u = u16 << 16;
  return v.f;
}

// first 16 blocks: pack W1/W2 into MFMA B-fragment order; rest: count + rank
// Bp[((nt*4+ks)*64+lane)*8 + j] = bf16(W[ks*32+(lane>>4)*8+j][nt*16+(lane&15)])
__global__ __launch_bounds__(256) void pack_count(
    const float* __restrict__ W1, const float* __restrict__ W2,
    short* __restrict__ Bp1, short* __restrict__ Bp2,
    const int* __restrict__ tgt, int* __restrict__ counts,
    int* __restrict__ rank, int E) {
  if (blockIdx.x < 16) {
    const int t = blockIdx.x * 256 + threadIdx.x;  // 0..4095
    const float* W = (t >> 11) ? W2 : W1;
    short* Bp = (t >> 11) ? Bp2 : Bp1;
    const int i = t & 2047;  // [nt(8)][ks(4)][lane(64)]
    const int lane = i & 63, ks = (i >> 6) & 3, nt = i >> 8;
    const int n = nt * 16 + (lane & 15);
    const int k0 = ks * 32 + ((lane >> 4) << 3);
    short8 v;
#pragma unroll
    for (int j = 0; j < 8; j++) v[j] = f2bf(W[(k0 + j) * H + n]);
    *reinterpret_cast<short8*>(Bp + (size_t)i * 8) = v;
  } else {
    const int e = (blockIdx.x - 16) * 256 + threadIdx.x;
    if (e < E) rank[e] = atomicAdd(&counts[tgt[e]], 1);
  }
}

// C[M,128] = relu(A[M,128] @ W + bias) (+R), A fp32 or bf16, C fp32 or bf16.
// 256 threads = 4 waves; B staged in LDS (shared); each wave owns 16 rows.
template <bool A_BF16, bool C_BF16, bool RESID>
__global__ __launch_bounds__(256) void gemm_mfma(
    const void* __restrict__ Av, const short* __restrict__ Bp,
    const float* __restrict__ bias, const float* __restrict__ R,
    void* __restrict__ Cv, int M) {
  __shared__ int4 bLds[2048];  // 32 KB: [nt(8)][ks(4)][lane(64)] x 16B
  const int tid = threadIdx.x;
  {
    const int4* g = reinterpret_cast<const int4*>(Bp);
#pragma unroll
    for (int i = 0; i < 8; i++) bLds[tid + i * 256] = g[tid + i * 256];
  }
  __syncthreads();

  const int wv = tid >> 6;
  const int lane = tid & 63;
  const int m0 = blockIdx.x * 64 + wv * 16;

  floatx4 acc[8];
#pragma unroll
  for (int nt = 0; nt < 8; nt++) acc[nt] = (floatx4)0.f;

  const int arow = lane & 15;
  const int kb = (lane >> 4) << 3;
  const short8* bL = reinterpret_cast<const short8*>(bLds);

#pragma unroll
  for (int ks = 0; ks < 4; ks++) {
    short8 af;
    {
      int row = min(m0 + arow, M - 1);  // clamp; garbage rows never stored
      const size_t off = (size_t)row * H + (ks << 5) + kb;
      if (A_BF16) {
        af = *reinterpret_cast<const short8*>((const short*)Av + off);
      } else {
        const float* ap = (const float*)Av + off;
        floatx4 x0 = *reinterpret_cast<const floatx4*>(ap);
        floatx4 x1 = *reinterpret_cast<const floatx4*>(ap + 4);
        af[0] = f2bf(x0[0]); af[1] = f2bf(x0[1]);
        af[2] = f2bf(x0[2]); af[3] = f2bf(x0[3]);
        af[4] = f2bf(x1[0]); af[5] = f2bf(x1[1]);
        af[6] = f2bf(x1[2]); af[7] = f2bf(x1[3]);
      }
    }
#pragma unroll
    for (int nt = 0; nt < 8; nt++) {
      const short8 bf = bL[((nt << 2) | ks) * 64 + lane];
      acc[nt] = __builtin_amdgcn_mfma_f32_16x16x32_bf16(af, bf, acc[nt], 0, 0, 0);
    }
  }

  // epilogue: C row = (lane>>4)*4 + reg, col = nt*16 + (lane&15)
  const int crow = (lane >> 4) << 2;
  const int ccol = lane & 15;
#pragma unroll
  for (int nt = 0; nt < 8; nt++) {
    const int col = (nt << 4) + ccol;
    const float bv = bias[col];
#pragma unroll
    for (int r = 0; r < 4; r++) {
      const int row = m0 + crow + r;
      if (row < M) {
        float v = fmaxf(acc[nt][r] + bv, 0.f);
        if (RESID) v += R[(size_t)row * H + col];
        if (C_BF16)
          ((short*)Cv)[(size_t)row * H + col] = f2bf(v);
        else
          ((float*)Cv)[(size_t)row * H + col] = v;
      }
    }
  }
}

// --- hierarchical scan: 1024 counts per block ---

__global__ __launch_bounds__(256) void scan_partial(
    const int* __restrict__ counts, int* __restrict__ blockSums, int N) {
  const int tid = threadIdx.x;
  const int base = blockIdx.x * 1024 + tid * 4;
  int4 v = make_int4(0, 0, 0, 0);
  if (base + 3 < N) {
    v = *reinterpret_cast<const int4*>(counts + base);
  } else if (base < N) {
    const int n = N - base;
    v.x = counts[base];
    if (n > 1) v.y = counts[base + 1];
    if (n > 2) v.z = counts[base + 2];
  }
  int s = v.x + v.y + v.z + v.w;
#pragma unroll
  for (int d = 1; d < 64; d <<= 1) s += __shfl_xor(s, d);
  __shared__ int ws[4];
  if ((tid & 63) == 0) ws[tid >> 6] = s;
  __syncthreads();
  if (tid == 0) blockSums[blockIdx.x] = ws[0] + ws[1] + ws[2] + ws[3];
}

__global__ __launch_bounds__(64) void scan_block_sums(
    int* __restrict__ blockSums, int nb) {
  const int lane = threadIdx.x;
  int carry = 0;
  for (int b = 0; b < nb; b += 64) {
    const int i = b + lane;
    const int v = (i < nb) ? blockSums[i] : 0;
    int x = v;
#pragma unroll
    for (int d = 1; d < 64; d <<= 1) {
      int t = __shfl_up(x, d);
      if (lane >= d) x += t;
    }
    if (i < nb) blockSums[i] = carry + x - v;  // exclusive
    carry += __shfl(x, 63);
  }
}

__global__ __launch_bounds__(256) void scan_final(
    const int* __restrict__ counts, const int* __restrict__ blockSums,
    int* __restrict__ offsets, int N, int E) {
  const int tid = threadIdx.x, lane = tid & 63, wv = tid >> 6;
  const int base = blockIdx.x * 1024 + tid * 4;
  int4 v = make_int4(0, 0, 0, 0);
  if (base + 3 < N) {
    v = *reinterpret_cast<const int4*>(counts + base);
  } else if (base < N) {
    const int n = N - base;
    v.x = counts[base];
    if (n > 1) v.y = counts[base + 1];
    if (n > 2) v.z = counts[base + 2];
  }
  const int s = v.x + v.y + v.z + v.w;
  int x = s;
#pragma unroll
  for (int d = 1; d < 64; d <<= 1) {
    int t = __shfl_up(x, d);
    if (lane >= d) x += t;
  }
  __shared__ int ws[4];
  if (lane == 63) ws[wv] = x;
  __syncthreads();
  int wbase = 0;
  for (int i = 0; i < wv; i++) wbase += ws[i];

  const int excl = blockSums[blockIdx.x] + wbase + (x - s);
  const int o0 = excl, o1 = o0 + v.x, o2 = o1 + v.y, o3 = o2 + v.z;
  if (base + 3 < N) {
    *reinterpret_cast<int4*>(offsets + base) = make_int4(o0, o1, o2, o3);
  } else if (base < N) {
    const int n = N - base;
    offsets[base] = o0;
    if (n > 1) offsets[base + 1] = o1;
    if (n > 2) offsets[base + 2] = o2;
  }
  if (blockIdx.x == 0 && tid == 0) offsets[N] = E;
}

// atomic-free scatter using precomputed rank
__global__ __launch_bounds__(256) void fill_edges(
    const int* __restrict__ src, const int* __restrict__ tgt,
    const float* __restrict__ norm, const int* __restrict__ offsets,
    const int* __restrict__ rank, int2* __restrict__ pairs, int E) {
  int e = blockIdx.x * blockDim.x + threadIdx.x;
  if (e >= E) return;
  const int pos = offsets[tgt[e]] + rank[e];
  pairs[pos] = make_int2(src[e], __float_as_int(norm[e]));
}

// one wave per node: gather bf16 Y rows, fp32 accumulate, bf16 store; ILP x8
__global__ __launch_bounds__(256) void pull_pool(
    const unsigned short* __restrict__ Y, const int2* __restrict__ pairs,
    const int* __restrict__ offsets, unsigned* __restrict__ pooled, int N) {
  const int node = blockIdx.x * 4 + (threadIdx.x >> 6);
  if (node >= N) return;
  const int lane = threadIdx.x & 63;
  int i = offsets[node];
  const int iend = offsets[node + 1];

  float ax = 0.f, ay = 0.f;
  for (; i + 7 < iend; i += 8) {
    int4 q[4];
    q[0] = *reinterpret_cast<const int4*>(pairs + i);
    q[1] = *reinterpret_cast<const int4*>(pairs + i + 2);
    q[2] = *reinterpret_cast<const int4*>(pairs + i + 4);
    q[3] = *reinterpret_cast<const int4*>(pairs + i + 6);
    unsigned v[8];
#pragma unroll
    for (int j = 0; j < 4; j++) {
      v[2 * j]     = *reinterpret_cast<const unsigned*>(Y + (size_t)q[j].x * H + lane * 2);
      v[2 * j + 1] = *reinterpret_cast<const unsigned*>(Y + (size_t)q[j].z * H + lane * 2);
    }
#pragma unroll
    for (int j = 0; j < 4; j++) {
      const float na = __int_as_float(q[j].y), nb = __int_as_float(q[j].w);
      ax = fmaf(na, bf2f(v[2 * j] & 0xffffu), ax);
      ay = fmaf(na, bf2f(v[2 * j] >> 16), ay);
      ax = fmaf(nb, bf2f(v[2 * j + 1] & 0xffffu), ax);
      ay = fmaf(nb, bf2f(v[2 * j + 1] >> 16), ay);
    }
  }
  for (; i < iend; i++) {
    const int2 p0 = pairs[i];
    const unsigned v0 = *reinterpret_cast<const unsigned*>(Y + (size_t)p0.x * H + lane * 2);
    const float n0 = __int_as_float(p0.y);
    ax = fmaf(n0, bf2f(v0 & 0xffffu), ax);
    ay = fmaf(n0, bf2f(v0 >> 16), ay);
  }
  pooled[(size_t)node * 64 + lane] =
      ((unsigned)(unsigned short)f2bf(ay) << 16) | (unsigned short)f2bf(ax);
}

extern "C" void kernel_launch(void* const* d_in, const int* in_sizes, int n_in,
                              void* d_out, int out_size, void* d_ws, size_t ws_size,
                              hipStream_t stream) {
  const float* X    = (const float*)d_in[0];
  const int*   src  = (const int*)d_in[1];
  const int*   tgt  = (const int*)d_in[2];
  const float* norm = (const float*)d_in[3];
  const float* W1   = (const float*)d_in[4];
  const float* b1   = (const float*)d_in[5];
  const float* W2   = (const float*)d_in[6];
  const float* b2   = (const float*)d_in[7];
  float* out = (float*)d_out;

  const int N = in_sizes[0] / H;   // 50000
  const int E = in_sizes[1];       // 800000

  // workspace carve (256B-aligned) — ~36 MB
  auto align_up = [](size_t x) { return (x + 255) & ~(size_t)255; };
  char* w = (char*)d_ws;
  unsigned short* Ybf   = (unsigned short*)w; w += align_up((size_t)N * H * 2);
  unsigned short* pool  = (unsigned short*)w; w += align_up((size_t)N * H * 2);
  int*   counts   = (int*)w;   w += align_up((size_t)N * sizeof(int));
  int*   offsets  = (int*)w;   w += align_up((size_t)(N + 1) * sizeof(int));
  int*   rank     = (int*)w;   w += align_up((size_t)E * sizeof(int));
  int*   blockSums= (int*)w;   w += align_up((size_t)1024 * sizeof(int));
  short* Bp1      = (short*)w; w += align_up((size_t)16384 * sizeof(short));
  short* Bp2      = (short*)w; w += align_up((size_t)16384 * sizeof(short));
  int2*  pairs    = (int2*)w;  w += align_up((size_t)E * sizeof(int2));

  hipMemsetAsync(counts, 0, (size_t)N * sizeof(int), stream);

  const int eb = (E + 255) / 256;  // 3125
  pack_count<<<eb + 16, 256, 0, stream>>>(W1, W2, Bp1, Bp2, tgt, counts, rank, E);

  const int gemm_blocks = (N + 63) / 64;  // 782
  gemm_mfma<false, true, false><<<gemm_blocks, 256, 0, stream>>>(
      X, Bp1, b1, nullptr, Ybf, N);

  const int nb = (N + 1023) / 1024;  // 49
  scan_partial<<<nb, 256, 0, stream>>>(counts, blockSums, N);
  scan_block_sums<<<1, 64, 0, stream>>>(blockSums, nb);
  scan_final<<<nb, 256, 0, stream>>>(counts, blockSums, offsets, N, E);

  fill_edges<<<eb, 256, 0, stream>>>(src, tgt, norm, offsets, rank, pairs, E);

  pull_pool<<<(N + 3) / 4, 256, 0, stream>>>(
      Ybf, pairs, offsets, (unsigned*)pool, N);

  gemm_mfma<true, false, true><<<gemm_blocks, 256, 0, stream>>>(
      pool, Bp2, b2, X, out, N);
}